// Round 2
// baseline (3862.719 us; speedup 1.0000x reference)
//
#include <hip/hip_runtime.h>
#include <math.h>

// Problem constants (fixed by setup_inputs)
namespace {
constexpr int Bt = 4096;
constexpr int Nt = 32;       // tokens per batch
constexpr int Dm = 256;      // model dim = N_HEAD*D_K = N_HEAD*D_V
constexpr int NHEAD = 8;
constexpr float NEGV = -10000000000.0f;
constexpr int ATTN_BASE = Bt * Dm;            // normed is first in d_out
constexpr float INV_TEMP = 0.17677669529663687f;  // 1/sqrt(D_K)=1/sqrt(32)

// Force a pointer into SGPRs (value is wave-uniform by construction).
__device__ __forceinline__ const float* uniform_ptr(const float* p) {
    unsigned long long u = (unsigned long long)p;
    unsigned lo = __builtin_amdgcn_readfirstlane((unsigned)u);
    unsigned hi = __builtin_amdgcn_readfirstlane((unsigned)(u >> 32));
    return (const float*)(((unsigned long long)hi << 32) | (unsigned long long)lo);
}

// Type-selected projection: acc[n] = sum_d xrow[n*Dm+d] * W[e(n)][d*Dm + j].
// xrow is a uniform (SGPR) pointer and all control flow is wave-uniform, so the
// x reads are scalar loads (s_load_dwordxN) on the scalar pipe: the projections
// issue ZERO LDS ops and the only VMEM is the per-lane weight column stream.
template <int NTOK>
__device__ __forceinline__ void project_su(const float* __restrict__ W, int j,
                                           const unsigned* tm,
                                           const float* __restrict__ xrow,
                                           float* acc)
{
#pragma unroll
    for (int n = 0; n < NTOK; ++n) acc[n] = 0.f;
#pragma unroll
    for (int e = 0; e < 4; ++e) {
        unsigned m = tm[e];
        if (m == 0) continue;
        const float* We = W + e * (Dm * Dm) + j;
        for (int d0 = 0; d0 < Dm; d0 += 16) {
            float w[16];
#pragma unroll
            for (int dd = 0; dd < 16; ++dd) w[dd] = We[(d0 + dd) * Dm];
#pragma unroll
            for (int n = 0; n < NTOK; ++n) {
                if (m & (1u << n)) {   // uniform: scalar branch, co-issues with VALU
                    const float* xr = xrow + n * Dm + d0;   // uniform address
#pragma unroll
                    for (int c = 0; c < 4; ++c) {
                        float4 xv = *(const float4*)(xr + c * 4);  // scalar load
                        acc[n] = fmaf(xv.x, w[c * 4 + 0], acc[n]);
                        acc[n] = fmaf(xv.y, w[c * 4 + 1], acc[n]);
                        acc[n] = fmaf(xv.z, w[c * 4 + 2], acc[n]);
                        acc[n] = fmaf(xv.w, w[c * 4 + 3], acc[n]);
                    }
                }
            }
        }
    }
}
} // namespace

// 512 threads: waves 0-3 (grp=0) project Q, waves 4-7 (grp=1) project K.
// x operands come via the scalar pipe; max live accumulator per thread = 32.
// launch_bounds min-waves=4 (VGPR cap 128): a misjudged live set costs a little
// occupancy instead of spilling to scratch (round-1 failure mode).
__global__ __launch_bounds__(512, 4)
void mha_fused_kernel(const float* __restrict__ q, const float* __restrict__ k,
                      const float* __restrict__ v,
                      const float* __restrict__ Wq, const float* __restrict__ Wk,
                      const float* __restrict__ Wv,
                      const float* __restrict__ rel_pri,
                      const float* __restrict__ fc_w, const float* __restrict__ fc_b,
                      const float* __restrict__ gamma, const float* __restrict__ beta,
                      const int* __restrict__ seq_etype, const int* __restrict__ seq_utype,
                      const int* __restrict__ mask,
                      float* __restrict__ out)
{
    const int b = blockIdx.x;
    const int t = threadIdx.x;      // 0..511
    const int j = t & 255;          // output column 0..255
    const int grp = t >> 8;         // 0: Q-side, 1: K-side (wave-uniform)
    const int h = j >> 5;           // head
    const int l = j & 31;           // lane within head (== token index for softmax)

    __shared__ __align__(16) float Klds[Nt][Dm];      // 32 KB K handoff
    __shared__ __align__(16) float outbuf[2][Dm];
    __shared__ __align__(16) float fcpart[2][Dm];
    __shared__ float attn_s[NHEAD][Nt];
    __shared__ float pri_s[Nt];
    __shared__ int   msks[Nt];
    __shared__ unsigned tmask_s[4];
    __shared__ int   ut_s;
    __shared__ float redA[4], redB[4];

    // ---- metadata ----
    if (t < 4) tmask_s[t] = 0u;
    if (t == 0) ut_s = seq_utype[b];
    __syncthreads();
    if (t < Nt) {
        int e = seq_etype[b * Nt + t];
        msks[t] = mask[b * Nt + t];
        pri_s[t] = rel_pri[ut_s * 4 + e] * INV_TEMP;
        atomicOr(&tmask_s[e], 1u << t);
    }
    __syncthreads();

    unsigned tm[4];
#pragma unroll
    for (int e = 0; e < 4; ++e) tm[e] = __builtin_amdgcn_readfirstlane(tmask_s[e]);
    const int ut = __builtin_amdgcn_readfirstlane(ut_s);

    // ---- Q (grp 0) / K (grp 1) projection, x via scalar pipe ----
    const float* xqk = uniform_ptr((grp ? k : q) + (size_t)b * (Nt * Dm));
    const float* Wqk = grp ? Wk : Wq;

    float acc[Nt];
    project_su<Nt>(Wqk, j, tm, xqk, acc);

    // ---- K handoff: group 1 publishes K columns to LDS ----
    if (grp) {
#pragma unroll
        for (int n = 0; n < Nt; ++n) Klds[n][j] = acc[n];   // bank = j&31, 2-way: free
    }
    __syncthreads();

    // ---- scores + softmax (group 0 only; acc == Qacc here) ----
    if (!grp) {
        float sc = 0.f;
#pragma unroll
        for (int n = 0; n < Nt; ++n) {
            float p = acc[n] * Klds[n][j];
#pragma unroll
            for (int off = 16; off >= 1; off >>= 1) p += __shfl_xor(p, off, 64);
            sc = (l == n) ? p : sc;
        }
        sc = sc * pri_s[l];
        if (msks[l] != 0) sc = NEGV;
        float mx = sc;
#pragma unroll
        for (int off = 16; off >= 1; off >>= 1) mx = fmaxf(mx, __shfl_xor(mx, off, 64));
        float ex = expf(sc - mx);
        float sum = ex;
#pragma unroll
        for (int off = 16; off >= 1; off >>= 1) sum += __shfl_xor(sum, off, 64);
        float at = ex / sum;
        attn_s[h][l] = at;
        // attn_flat[(h*B + b)*N + n]
        out[ATTN_BASE + h * (Bt * Nt) + b * Nt + l] = at;
    }
    __syncthreads();   // Klds dead, attn_s visible to all

    // ---- V projection: token-split across groups (grp 0: tokens 0..15, grp 1: 16..31) ----
    const int tokbase = grp ? 16 : 0;
    unsigned tmv[4];
#pragma unroll
    for (int e = 0; e < 4; ++e)
        tmv[e] = __builtin_amdgcn_readfirstlane(grp ? (tm[e] >> 16) : (tm[e] & 0xFFFFu));
    const float* xv = uniform_ptr(v + (size_t)b * (Nt * Dm) + tokbase * Dm);

    float vacc[16];
    project_su<16>(Wv, j, tmv, xv, vacc);

    // ---- attention output (partial per group): o[j] = sum_n attn[h][n] * V[n][j] ----
    float o = 0.f;
#pragma unroll
    for (int n = 0; n < 16; ++n) o = fmaf(attn_s[h][tokbase + n], vacc[n], o);
    outbuf[grp][j] = o;
    __syncthreads();

    // ---- fc: i-range split across groups; proj[j] = fc_b[ut][j] + sum_i out[i] * fc_w[ut][i][j] ----
    const float* Wf = fc_w + ut * (Dm * Dm) + j;
    float pj = grp ? 0.f : fc_b[ut * Dm + j];
    {
        const int ibase = grp * 128;
        for (int i0 = 0; i0 < 128; i0 += 4) {
            float4 a0 = *(const float4*)&outbuf[0][ibase + i0];
            float4 a1 = *(const float4*)&outbuf[1][ibase + i0];
            pj = fmaf(a0.x + a1.x, Wf[(ibase + i0 + 0) * Dm], pj);
            pj = fmaf(a0.y + a1.y, Wf[(ibase + i0 + 1) * Dm], pj);
            pj = fmaf(a0.z + a1.z, Wf[(ibase + i0 + 2) * Dm], pj);
            pj = fmaf(a0.w + a1.w, Wf[(ibase + i0 + 3) * Dm], pj);
        }
    }
    fcpart[grp][j] = pj;
    __syncthreads();

    // ---- LayerNorm over 256 columns (group 0; reduction across its 4 waves) ----
    if (!grp) {
        float pjf = fcpart[0][j] + fcpart[1][j];
        float s1 = pjf, s2 = pjf * pjf;
#pragma unroll
        for (int off = 32; off >= 1; off >>= 1) {
            s1 += __shfl_xor(s1, off, 64);
            s2 += __shfl_xor(s2, off, 64);
        }
        const int w = j >> 6;
        if ((j & 63) == 0) { redA[w] = s1; redB[w] = s2; }
    }
    __syncthreads();
    if (!grp) {
        float pjf = fcpart[0][j] + fcpart[1][j];
        float t1 = redA[0] + redA[1] + redA[2] + redA[3];
        float t2 = redB[0] + redB[1] + redB[2] + redB[3];
        float mu = t1 * (1.f / 256.f);
        float var = t2 * (1.f / 256.f) - mu * mu;
        float inv = rsqrtf(var + 1e-5f);
        out[b * Dm + j] = (pjf - mu) * inv * gamma[j] + beta[j];
    }
}

extern "C" void kernel_launch(void* const* d_in, const int* in_sizes, int n_in,
                              void* d_out, int out_size, void* d_ws, size_t ws_size,
                              hipStream_t stream) {
    const float* q       = (const float*)d_in[0];
    const float* k       = (const float*)d_in[1];
    const float* v       = (const float*)d_in[2];
    const float* Wq      = (const float*)d_in[3];
    const float* Wk      = (const float*)d_in[4];
    const float* Wv      = (const float*)d_in[5];
    const float* rel_pri = (const float*)d_in[6];
    const float* fc_w    = (const float*)d_in[7];
    const float* fc_b    = (const float*)d_in[8];
    const float* gamma   = (const float*)d_in[9];
    const float* beta    = (const float*)d_in[10];
    const int* seq_etype = (const int*)d_in[11];
    const int* seq_utype = (const int*)d_in[12];
    const int* mask      = (const int*)d_in[13];
    float* outp = (float*)d_out;

    mha_fused_kernel<<<Bt, 512, 0, stream>>>(q, k, v, Wq, Wk, Wv, rel_pri,
                                             fc_w, fc_b, gamma, beta,
                                             seq_etype, seq_utype, mask, outp);
}

// Round 3
// 1592.264 us; speedup vs baseline: 2.4259x; 2.4259x over previous
//
#include <hip/hip_runtime.h>
#include <math.h>

// Problem constants (fixed by setup_inputs)
namespace {
constexpr int Bt = 4096;
constexpr int Nt = 32;       // tokens per batch
constexpr int Dm = 256;      // model dim = N_HEAD*D_K = N_HEAD*D_V
constexpr int DH = 128;      // d-half staged in LDS at a time (halves LDS -> 8 blocks/CU)
constexpr int NHEAD = 8;
constexpr float NEGV = -10000000000.0f;
constexpr int ATTN_BASE = Bt * Dm;            // normed is first in d_out
constexpr float INV_TEMP = 0.17677669529663687f;  // 1/sqrt(D_K)=1/sqrt(32)

// Type-selected projection over one d-half:
//   acc[n] += sum_{d in [rowbase,rowbase+DH)} xs[n][d-rowbase] * W[e(n)][d][j]
// tm[e] = 32-bit bitmask of tokens with type e (wave-uniform -> scalar branches).
__device__ __forceinline__ void project_half(const float* __restrict__ W, int j,
                                             const unsigned* tm,
                                             const float (*xs)[DH], int rowbase,
                                             float* acc)
{
#pragma unroll
    for (int e = 0; e < 4; ++e) {
        unsigned m = tm[e];
        if (m == 0) continue;
        const float* We = W + e * (Dm * Dm) + rowbase * Dm + j;
        for (int d0 = 0; d0 < DH; d0 += 16) {
            float w[16];
#pragma unroll
            for (int dd = 0; dd < 16; ++dd) w[dd] = We[(d0 + dd) * Dm];
#pragma unroll
            for (int n = 0; n < Nt; ++n) {
                if (m & (1u << n)) {   // uniform: s_and + s_cbranch, co-issues with VALU
#pragma unroll
                    for (int c = 0; c < 4; ++c) {
                        float4 xv = *(const float4*)&xs[n][d0 + c * 4];
                        acc[n] = fmaf(xv.x, w[c * 4 + 0], acc[n]);
                        acc[n] = fmaf(xv.y, w[c * 4 + 1], acc[n]);
                        acc[n] = fmaf(xv.z, w[c * 4 + 2], acc[n]);
                        acc[n] = fmaf(xv.w, w[c * 4 + 3], acc[n]);
                    }
                }
            }
        }
    }
}
} // namespace

// Round-0 structure (proven 1334us, 64 VGPR) with ONE change: x staged in
// d-halves so LDS/block ~18.7KB -> 8 blocks/CU -> 32 waves/CU (was 16).
__global__ __launch_bounds__(256)
void mha_fused_kernel(const float* __restrict__ q, const float* __restrict__ k,
                      const float* __restrict__ v,
                      const float* __restrict__ Wq, const float* __restrict__ Wk,
                      const float* __restrict__ Wv,
                      const float* __restrict__ rel_pri,
                      const float* __restrict__ fc_w, const float* __restrict__ fc_b,
                      const float* __restrict__ gamma, const float* __restrict__ beta,
                      const int* __restrict__ seq_etype, const int* __restrict__ seq_utype,
                      const int* __restrict__ mask,
                      float* __restrict__ out)
{
    const int b = blockIdx.x;
    const int j = threadIdx.x;      // output column 0..255
    const int h = j >> 5;           // head
    const int l = j & 31;           // lane within head (== token index for softmax)

    __shared__ __align__(16) float xs[Nt][DH];   // 16 KB staging (d-half of q/k/v)
    __shared__ __align__(16) float outbuf[Dm];
    __shared__ float attn_s[NHEAD][Nt];
    __shared__ float pri_s[Nt];
    __shared__ int   msks[Nt];
    __shared__ unsigned tmask_s[4];
    __shared__ int   ut_s;
    __shared__ float redA[4], redB[4];

    // ---- metadata ----
    if (j < 4) tmask_s[j] = 0u;
    if (j == 0) ut_s = seq_utype[b];
    __syncthreads();
    if (j < Nt) {
        int e = seq_etype[b * Nt + j];
        msks[j] = mask[b * Nt + j];
        pri_s[j] = rel_pri[ut_s * 4 + e] * INV_TEMP;
        atomicOr(&tmask_s[e], 1u << j);
    }
    __syncthreads();

    unsigned tm[4];
#pragma unroll
    for (int e = 0; e < 4; ++e) tm[e] = __builtin_amdgcn_readfirstlane(tmask_s[e]);
    const int ut = __builtin_amdgcn_readfirstlane(ut_s);

    float4* d4 = (float4*)&xs[0][0];   // 1024 float4 per half; 4 per thread

    // ---- Q projection (d-halves) ----
    const float4* sq = (const float4*)(q + (size_t)b * (Nt * Dm));
    float Qacc[Nt];
#pragma unroll
    for (int n = 0; n < Nt; ++n) Qacc[n] = 0.f;
#pragma unroll
    for (int half = 0; half < 2; ++half) {
#pragma unroll
        for (int r = 0; r < 4; ++r) {
            int i = r * 256 + j;            // 0..1023 = n*32 + c
            int n = i >> 5, c = i & 31;
            d4[i] = sq[n * 64 + half * 32 + c];
        }
        __syncthreads();
        project_half(Wq, j, tm, xs, half * DH, Qacc);
        __syncthreads();   // readers done before next stage overwrites
    }

    // ---- K projection (d-halves) ----
    const float4* sk = (const float4*)(k + (size_t)b * (Nt * Dm));
    float Kacc[Nt];
#pragma unroll
    for (int n = 0; n < Nt; ++n) Kacc[n] = 0.f;
#pragma unroll
    for (int half = 0; half < 2; ++half) {
#pragma unroll
        for (int r = 0; r < 4; ++r) {
            int i = r * 256 + j;
            int n = i >> 5, c = i & 31;
            d4[i] = sk[n * 64 + half * 32 + c];
        }
        __syncthreads();
        project_half(Wk, j, tm, xs, half * DH, Kacc);
        __syncthreads();
    }

    // ---- scores: sc = score for token l of head h (reduce over 32 cols of head) ----
    float sc = 0.f;
#pragma unroll
    for (int n = 0; n < Nt; ++n) {
        float p = Qacc[n] * Kacc[n];
#pragma unroll
        for (int off = 16; off >= 1; off >>= 1) p += __shfl_xor(p, off, 64);
        sc = (l == n) ? p : sc;
    }

    // ---- scale, mask, softmax over 32 tokens (lanes of 32-group) ----
    sc = sc * pri_s[l];
    if (msks[l] != 0) sc = NEGV;
    float mx = sc;
#pragma unroll
    for (int off = 16; off >= 1; off >>= 1) mx = fmaxf(mx, __shfl_xor(mx, off, 64));
    float ex = expf(sc - mx);
    float sum = ex;
#pragma unroll
    for (int off = 16; off >= 1; off >>= 1) sum += __shfl_xor(sum, off, 64);
    float at = ex / sum;
    attn_s[h][l] = at;
    // attn_flat[(h*B + b)*N + n]
    out[ATTN_BASE + h * (Bt * Nt) + b * Nt + l] = at;

    // ---- V projection (d-halves) ----
    const float4* sv = (const float4*)(v + (size_t)b * (Nt * Dm));
    float Vacc[Nt];
#pragma unroll
    for (int n = 0; n < Nt; ++n) Vacc[n] = 0.f;
#pragma unroll
    for (int half = 0; half < 2; ++half) {
        __syncthreads();   // previous xs readers done (incl. K-half readers / attn writes)
#pragma unroll
        for (int r = 0; r < 4; ++r) {
            int i = r * 256 + j;
            int n = i >> 5, c = i & 31;
            d4[i] = sv[n * 64 + half * 32 + c];
        }
        __syncthreads();
        project_half(Wv, j, tm, xs, half * DH, Vacc);
    }
    __syncthreads();

    // ---- attention output: o[j] = sum_n attn[h][n] * V[n][j] ----
    float o = 0.f;
#pragma unroll
    for (int n = 0; n < Nt; ++n) o = fmaf(attn_s[h][n], Vacc[n], o);
    outbuf[j] = o;
    __syncthreads();

    // ---- fc: proj[j] = fc_b[ut][j] + sum_i outbuf[i] * fc_w[ut][i][j] ----
    const float* Wf = fc_w + ut * (Dm * Dm) + j;
    float pj = fc_b[ut * Dm + j];
    for (int i0 = 0; i0 < Dm; i0 += 4) {
        float4 ov = *(const float4*)&outbuf[i0];
        pj = fmaf(ov.x, Wf[(i0 + 0) * Dm], pj);
        pj = fmaf(ov.y, Wf[(i0 + 1) * Dm], pj);
        pj = fmaf(ov.z, Wf[(i0 + 2) * Dm], pj);
        pj = fmaf(ov.w, Wf[(i0 + 3) * Dm], pj);
    }

    // ---- LayerNorm over 256 columns (block-wide reduction) ----
    float s1 = pj, s2 = pj * pj;
#pragma unroll
    for (int off = 32; off >= 1; off >>= 1) {
        s1 += __shfl_xor(s1, off, 64);
        s2 += __shfl_xor(s2, off, 64);
    }
    const int w = j >> 6;
    if ((j & 63) == 0) { redA[w] = s1; redB[w] = s2; }
    __syncthreads();
    float t1 = redA[0] + redA[1] + redA[2] + redA[3];
    float t2 = redB[0] + redB[1] + redB[2] + redB[3];
    float mu = t1 * (1.f / 256.f);
    float var = t2 * (1.f / 256.f) - mu * mu;
    float inv = rsqrtf(var + 1e-5f);
    out[b * Dm + j] = (pj - mu) * inv * gamma[j] + beta[j];
}

extern "C" void kernel_launch(void* const* d_in, const int* in_sizes, int n_in,
                              void* d_out, int out_size, void* d_ws, size_t ws_size,
                              hipStream_t stream) {
    const float* q       = (const float*)d_in[0];
    const float* k       = (const float*)d_in[1];
    const float* v       = (const float*)d_in[2];
    const float* Wq      = (const float*)d_in[3];
    const float* Wk      = (const float*)d_in[4];
    const float* Wv      = (const float*)d_in[5];
    const float* rel_pri = (const float*)d_in[6];
    const float* fc_w    = (const float*)d_in[7];
    const float* fc_b    = (const float*)d_in[8];
    const float* gamma   = (const float*)d_in[9];
    const float* beta    = (const float*)d_in[10];
    const int* seq_etype = (const int*)d_in[11];
    const int* seq_utype = (const int*)d_in[12];
    const int* mask      = (const int*)d_in[13];
    float* outp = (float*)d_out;

    mha_fused_kernel<<<Bt, 256, 0, stream>>>(q, k, v, Wq, Wk, Wv, rel_pri,
                                             fc_w, fc_b, gamma, beta,
                                             seq_etype, seq_utype, mask, outp);
}

// Round 4
// 1336.882 us; speedup vs baseline: 2.8893x; 1.1910x over previous
//
#include <hip/hip_runtime.h>
#include <math.h>

// Problem constants (fixed by setup_inputs)
namespace {
constexpr int Bt = 4096;
constexpr int Nt = 32;       // tokens per batch
constexpr int Dm = 256;      // model dim = N_HEAD*D_K = N_HEAD*D_V
constexpr int DH = 128;      // d-half staged in LDS at a time
constexpr int NHEAD = 8;
constexpr float NEGV = -10000000000.0f;
constexpr int ATTN_BASE = Bt * Dm;            // normed is first in d_out
constexpr float INV_TEMP = 0.17677669529663687f;  // 1/sqrt(D_K)=1/sqrt(32)

// Type-selected projection over one d-half:
//   acc[n] += sum_{d in [rowbase,rowbase+DH)} xs[n][d-rowbase] * W[e(n)][d][j]
// tm[e] = 32-bit bitmask of tokens with type e (wave-uniform -> scalar branches).
__device__ __forceinline__ void project_half(const float* __restrict__ W, int j,
                                             const unsigned* tm,
                                             const float (*xs)[DH], int rowbase,
                                             float* acc)
{
#pragma unroll
    for (int e = 0; e < 4; ++e) {
        unsigned m = tm[e];
        if (m == 0) continue;
        const float* We = W + e * (Dm * Dm) + rowbase * Dm + j;
        for (int d0 = 0; d0 < DH; d0 += 16) {
            float w[16];
#pragma unroll
            for (int dd = 0; dd < 16; ++dd) w[dd] = We[(d0 + dd) * Dm];
#pragma unroll
            for (int n = 0; n < Nt; ++n) {
                if (m & (1u << n)) {   // uniform: s_and + s_cbranch, co-issues with VALU
#pragma unroll
                    for (int c = 0; c < 4; ++c) {
                        float4 xv = *(const float4*)&xs[n][d0 + c * 4];
                        acc[n] = fmaf(xv.x, w[c * 4 + 0], acc[n]);
                        acc[n] = fmaf(xv.y, w[c * 4 + 1], acc[n]);
                        acc[n] = fmaf(xv.z, w[c * 4 + 2], acc[n]);
                        acc[n] = fmaf(xv.w, w[c * 4 + 3], acc[n]);
                    }
                }
            }
        }
    }
}
} // namespace

// Empirical law from rounds 0/1/3: resident blocks/CU is pinned at ~4 regardless
// of LDS/VGPR headroom -> waves/CU = 4 x waves-per-block. So: 512-thread blocks,
// TWO independent batches per block (threads 0-255 -> batch 2b, 256-511 -> 2b+1),
// each half running round-3's proven 60-VGPR per-thread code on its own LDS half.
// 32 waves/CU expected (was 14). No launch_bounds VGPR cap (round-1 spill lesson).
__global__ __launch_bounds__(512)
void mha_fused_kernel(const float* __restrict__ q, const float* __restrict__ k,
                      const float* __restrict__ v,
                      const float* __restrict__ Wq, const float* __restrict__ Wk,
                      const float* __restrict__ Wv,
                      const float* __restrict__ rel_pri,
                      const float* __restrict__ fc_w, const float* __restrict__ fc_b,
                      const float* __restrict__ gamma, const float* __restrict__ beta,
                      const int* __restrict__ seq_etype, const int* __restrict__ seq_utype,
                      const int* __restrict__ mask,
                      float* __restrict__ out)
{
    const int t = threadIdx.x;      // 0..511
    const int grp = t >> 8;         // which batch of the pair (wave-uniform)
    const int j = t & 255;          // output column 0..255
    const int bb = blockIdx.x * 2 + grp;   // batch index
    const int h = j >> 5;           // head
    const int l = j & 31;           // lane within head (== token index for softmax)

    __shared__ __align__(16) float xs[2][Nt][DH];   // 2 x 16 KB staging
    __shared__ __align__(16) float outbuf[2][Dm];
    __shared__ float attn_s[2][NHEAD][Nt];
    __shared__ float pri_s[2][Nt];
    __shared__ int   msks[2][Nt];
    __shared__ unsigned tmask_s[2][4];
    __shared__ int   ut_s[2];
    __shared__ float redA[2][4], redB[2][4];

    // ---- metadata (each half for its own batch) ----
    if (j < 4) tmask_s[grp][j] = 0u;
    if (j == 0) ut_s[grp] = seq_utype[bb];
    __syncthreads();
    if (j < Nt) {
        int e = seq_etype[bb * Nt + j];
        msks[grp][j] = mask[bb * Nt + j];
        pri_s[grp][j] = rel_pri[ut_s[grp] * 4 + e] * INV_TEMP;
        atomicOr(&tmask_s[grp][e], 1u << j);
    }
    __syncthreads();

    unsigned tm[4];
#pragma unroll
    for (int e = 0; e < 4; ++e) tm[e] = __builtin_amdgcn_readfirstlane(tmask_s[grp][e]);
    const int ut = __builtin_amdgcn_readfirstlane(ut_s[grp]);

    float4* d4 = (float4*)&xs[grp][0][0];   // 1024 float4 per half; 4 per thread

    // ---- Q projection (d-halves) ----
    const float4* sq = (const float4*)(q + (size_t)bb * (Nt * Dm));
    float Qacc[Nt];
#pragma unroll
    for (int n = 0; n < Nt; ++n) Qacc[n] = 0.f;
#pragma unroll
    for (int half = 0; half < 2; ++half) {
#pragma unroll
        for (int r = 0; r < 4; ++r) {
            int i = r * 256 + j;            // 0..1023 = n*32 + c
            int n = i >> 5, c = i & 31;
            d4[i] = sq[n * 64 + half * 32 + c];
        }
        __syncthreads();
        project_half(Wq, j, tm, xs[grp], half * DH, Qacc);
        __syncthreads();   // readers done before next stage overwrites
    }

    // ---- K projection (d-halves) ----
    const float4* sk = (const float4*)(k + (size_t)bb * (Nt * Dm));
    float Kacc[Nt];
#pragma unroll
    for (int n = 0; n < Nt; ++n) Kacc[n] = 0.f;
#pragma unroll
    for (int half = 0; half < 2; ++half) {
#pragma unroll
        for (int r = 0; r < 4; ++r) {
            int i = r * 256 + j;
            int n = i >> 5, c = i & 31;
            d4[i] = sk[n * 64 + half * 32 + c];
        }
        __syncthreads();
        project_half(Wk, j, tm, xs[grp], half * DH, Kacc);
        __syncthreads();
    }

    // ---- scores: sc = score for token l of head h (reduce over 32 cols of head) ----
    float sc = 0.f;
#pragma unroll
    for (int n = 0; n < Nt; ++n) {
        float p = Qacc[n] * Kacc[n];
#pragma unroll
        for (int off = 16; off >= 1; off >>= 1) p += __shfl_xor(p, off, 64);
        sc = (l == n) ? p : sc;
    }

    // ---- scale, mask, softmax over 32 tokens (lanes of 32-group) ----
    sc = sc * pri_s[grp][l];
    if (msks[grp][l] != 0) sc = NEGV;
    float mx = sc;
#pragma unroll
    for (int off = 16; off >= 1; off >>= 1) mx = fmaxf(mx, __shfl_xor(mx, off, 64));
    float ex = expf(sc - mx);
    float sum = ex;
#pragma unroll
    for (int off = 16; off >= 1; off >>= 1) sum += __shfl_xor(sum, off, 64);
    float at = ex / sum;
    attn_s[grp][h][l] = at;
    // attn_flat[(h*B + b)*N + n]
    out[ATTN_BASE + h * (Bt * Nt) + bb * Nt + l] = at;

    // ---- V projection (d-halves) ----
    const float4* sv = (const float4*)(v + (size_t)bb * (Nt * Dm));
    float Vacc[Nt];
#pragma unroll
    for (int n = 0; n < Nt; ++n) Vacc[n] = 0.f;
#pragma unroll
    for (int half = 0; half < 2; ++half) {
        __syncthreads();   // previous xs readers done
#pragma unroll
        for (int r = 0; r < 4; ++r) {
            int i = r * 256 + j;
            int n = i >> 5, c = i & 31;
            d4[i] = sv[n * 64 + half * 32 + c];
        }
        __syncthreads();
        project_half(Wv, j, tm, xs[grp], half * DH, Vacc);
    }
    __syncthreads();

    // ---- attention output: o[j] = sum_n attn[h][n] * V[n][j] ----
    float o = 0.f;
#pragma unroll
    for (int n = 0; n < Nt; ++n) o = fmaf(attn_s[grp][h][n], Vacc[n], o);
    outbuf[grp][j] = o;
    __syncthreads();

    // ---- fc: proj[j] = fc_b[ut][j] + sum_i outbuf[i] * fc_w[ut][i][j] ----
    const float* Wf = fc_w + ut * (Dm * Dm) + j;
    float pj = fc_b[ut * Dm + j];
    for (int i0 = 0; i0 < Dm; i0 += 4) {
        float4 ov = *(const float4*)&outbuf[grp][i0];
        pj = fmaf(ov.x, Wf[(i0 + 0) * Dm], pj);
        pj = fmaf(ov.y, Wf[(i0 + 1) * Dm], pj);
        pj = fmaf(ov.z, Wf[(i0 + 2) * Dm], pj);
        pj = fmaf(ov.w, Wf[(i0 + 3) * Dm], pj);
    }

    // ---- LayerNorm over 256 columns (per-half reduction across its 4 waves) ----
    float s1 = pj, s2 = pj * pj;
#pragma unroll
    for (int off = 32; off >= 1; off >>= 1) {
        s1 += __shfl_xor(s1, off, 64);
        s2 += __shfl_xor(s2, off, 64);
    }
    const int w = (t >> 6) & 3;     // wave within half
    if ((j & 63) == 0) { redA[grp][w] = s1; redB[grp][w] = s2; }
    __syncthreads();
    float t1 = redA[grp][0] + redA[grp][1] + redA[grp][2] + redA[grp][3];
    float t2 = redB[grp][0] + redB[grp][1] + redB[grp][2] + redB[grp][3];
    float mu = t1 * (1.f / 256.f);
    float var = t2 * (1.f / 256.f) - mu * mu;
    float inv = rsqrtf(var + 1e-5f);
    out[bb * Dm + j] = (pj - mu) * inv * gamma[j] + beta[j];
}

extern "C" void kernel_launch(void* const* d_in, const int* in_sizes, int n_in,
                              void* d_out, int out_size, void* d_ws, size_t ws_size,
                              hipStream_t stream) {
    const float* q       = (const float*)d_in[0];
    const float* k       = (const float*)d_in[1];
    const float* v       = (const float*)d_in[2];
    const float* Wq      = (const float*)d_in[3];
    const float* Wk      = (const float*)d_in[4];
    const float* Wv      = (const float*)d_in[5];
    const float* rel_pri = (const float*)d_in[6];
    const float* fc_w    = (const float*)d_in[7];
    const float* fc_b    = (const float*)d_in[8];
    const float* gamma   = (const float*)d_in[9];
    const float* beta    = (const float*)d_in[10];
    const int* seq_etype = (const int*)d_in[11];
    const int* seq_utype = (const int*)d_in[12];
    const int* mask      = (const int*)d_in[13];
    float* outp = (float*)d_out;

    mha_fused_kernel<<<Bt / 2, 512, 0, stream>>>(q, k, v, Wq, Wk, Wv, rel_pri,
                                                 fc_w, fc_b, gamma, beta,
                                                 seq_etype, seq_utype, mask, outp);
}